// Round 1
// baseline (747.298 us; speedup 1.0000x reference)
//
#include <hip/hip_runtime.h>

typedef unsigned short u16;
typedef unsigned int   u32;
typedef __attribute__((ext_vector_type(8))) __bf16 bf16x8;
typedef __attribute__((ext_vector_type(4))) float  f32x4;

#define BB   16
#define CH   256
#define HW   2304
#define SEQ  2048
#define EMB  256
#define CTXD 128
#define OUT0 9437184   // 16*256*2304, float offset of att region in d_out
#define NQT  72        // HW/32
#define SLOTF 65536    // floats per att slot (32*2048)

#define MFMA(a,b,c) __builtin_amdgcn_mfma_f32_16x16x32_bf16(a,b,c,0,0,0)

__device__ __forceinline__ u16 f2bf(float f){
  u32 u = __builtin_bit_cast(u32, f);
  u += 0x7fffu + ((u >> 16) & 1u);
  return (u16)(u >> 16);
}
__device__ __forceinline__ float bf2f(u32 us){ return __builtin_bit_cast(float, us << 16); }

__device__ __forceinline__ bf16x8 ld16(const u16* p){
  uint4 q = *reinterpret_cast<const uint4*>(p);
  return __builtin_bit_cast(bf16x8, q);
}
__device__ __forceinline__ bf16x8 mk8(float a0,float a1,float a2,float a3,
                                      float a4,float a5,float a6,float a7){
  uint4 q;
  q.x = (u32)f2bf(a0) | ((u32)f2bf(a1) << 16);
  q.y = (u32)f2bf(a2) | ((u32)f2bf(a3) << 16);
  q.z = (u32)f2bf(a4) | ((u32)f2bf(a5) << 16);
  q.w = (u32)f2bf(a6) | ((u32)f2bf(a7) << 16);
  return __builtin_bit_cast(bf16x8, q);
}

// ---------------- K0: weight prep -------------------------------------------
// blocks 0..255: Wqin[e][c] = sum_f Wq[e][f]*W_in[f][c]; thread0: bq_eff[e]
// blocks 256..319: bf16 conversion of Wk, Wv, W_out
__global__ __launch_bounds__(256) void k_prep(
    const float* __restrict__ Wq, const float* __restrict__ W_in,
    const float* __restrict__ b_in, const float* __restrict__ bq,
    const float* __restrict__ Wk, const float* __restrict__ Wv,
    const float* __restrict__ Wout,
    u16* __restrict__ WqinBf, u16* __restrict__ WkBf, u16* __restrict__ WvBf,
    u16* __restrict__ WoutBf, float* __restrict__ bq_eff)
{
  int blk = blockIdx.x, t = threadIdx.x;
  if (blk < 256) {
    int e = blk, c = t;
    float s = 0.f;
    for (int f = 0; f < 256; f++) s += Wq[e*256+f] * W_in[f*256+c];
    WqinBf[e*256+c] = f2bf(s);
    if (t == 0) {
      float bb = bq[e];
      for (int f = 0; f < 256; f++) bb += Wq[e*256+f] * b_in[f];
      bq_eff[e] = bb;
    }
  } else {
    u32 flat = (u32)(blk - 256) * 256 + t;
    for (u32 idx = flat; idx < 131072u; idx += 16384u) {
      if (idx < 32768u)       WkBf[idx]          = f2bf(Wk[idx]);
      else if (idx < 65536u)  WvBf[idx - 32768u] = f2bf(Wv[idx - 32768u]);
      else                    WoutBf[idx - 65536u] = f2bf(Wout[idx - 65536u]);
    }
  }
}

// ---------------- K1: Q projection ------------------------------------------
// D[e][i] = sum_c Wqin[e][c] * x[b][c][i];  store Q[b][i][e] (bf16)
__global__ __launch_bounds__(256) void k_qproj(
    const float* __restrict__ x, const u16* __restrict__ WqinBf,
    const float* __restrict__ bq_eff, u16* __restrict__ Qbf)
{
  int b = blockIdx.y, ibase = blockIdx.x * 64;
  int t = threadIdx.x, wv = t >> 6, lane = t & 63, g4 = lane >> 4, r16 = lane & 15;
  int e0 = wv * 64;
  f32x4 acc[4][4] = {};
  #pragma unroll 2
  for (int kk = 0; kk < 8; kk++) {
    bf16x8 a[4];
    #pragma unroll
    for (int m = 0; m < 4; m++)
      a[m] = ld16(WqinBf + (size_t)(e0 + m*16 + r16) * 256 + kk*32 + g4*8);
    bf16x8 bb[4];
    #pragma unroll
    for (int n = 0; n < 4; n++) {
      const float* xp = x + ((size_t)b*CH + kk*32 + g4*8) * HW + ibase + n*16 + r16;
      bb[n] = mk8(xp[0], xp[HW], xp[2*HW], xp[3*HW], xp[4*HW], xp[5*HW], xp[6*HW], xp[7*HW]);
    }
    #pragma unroll
    for (int m = 0; m < 4; m++)
      #pragma unroll
      for (int n = 0; n < 4; n++)
        acc[m][n] = MFMA(a[m], bb[n], acc[m][n]);
  }
  #pragma unroll
  for (int m = 0; m < 4; m++) {
    int e = e0 + m*16 + g4*4;
    float b0 = bq_eff[e], b1 = bq_eff[e+1], b2 = bq_eff[e+2], b3 = bq_eff[e+3];
    #pragma unroll
    for (int n = 0; n < 4; n++) {
      int i = ibase + n*16 + r16;
      u32 lo = (u32)f2bf(acc[m][n][0] + b0) | ((u32)f2bf(acc[m][n][1] + b1) << 16);
      u32 hi = (u32)f2bf(acc[m][n][2] + b2) | ((u32)f2bf(acc[m][n][3] + b3) << 16);
      *(uint2*)(Qbf + ((size_t)b*HW + i) * EMB + e) = make_uint2(lo, hi);
    }
  }
}

// ---------------- K2: K & V projections -------------------------------------
// waves 0-3: K[b][s][e]; waves 4-7: Vt[b][e][s]
__global__ __launch_bounds__(512) void k_kvproj(
    const float* __restrict__ ctx, const u16* __restrict__ WkBf, const u16* __restrict__ WvBf,
    const float* __restrict__ bk, const float* __restrict__ bv,
    u16* __restrict__ Kbf, u16* __restrict__ Vtb)
{
  int b = blockIdx.y, sbase = blockIdx.x * 64;
  int t = threadIdx.x, wv = t >> 6, lane = t & 63, g4 = lane >> 4, r16 = lane & 15;
  bool isV = wv >= 4;
  int e0 = (wv & 3) * 64;
  const u16* Wsel = isV ? WvBf : WkBf;
  f32x4 acc[4][4] = {};
  #pragma unroll
  for (int kk = 0; kk < 4; kk++) {
    bf16x8 a[4];
    #pragma unroll
    for (int m = 0; m < 4; m++)
      a[m] = ld16(Wsel + (size_t)(e0 + m*16 + r16) * 128 + kk*32 + g4*8);
    bf16x8 bb[4];
    #pragma unroll
    for (int n = 0; n < 4; n++) {
      const float* cp = ctx + ((size_t)b*SEQ + sbase + n*16 + r16) * CTXD + kk*32 + g4*8;
      float4 lo = *(const float4*)cp;
      float4 hi = *(const float4*)(cp + 4);
      bb[n] = mk8(lo.x, lo.y, lo.z, lo.w, hi.x, hi.y, hi.z, hi.w);
    }
    #pragma unroll
    for (int m = 0; m < 4; m++)
      #pragma unroll
      for (int n = 0; n < 4; n++)
        acc[m][n] = MFMA(a[m], bb[n], acc[m][n]);
  }
  if (!isV) {
    #pragma unroll
    for (int m = 0; m < 4; m++) {
      int e = e0 + m*16 + g4*4;
      float b0 = bk[e], b1 = bk[e+1], b2 = bk[e+2], b3 = bk[e+3];
      #pragma unroll
      for (int n = 0; n < 4; n++) {
        int s = sbase + n*16 + r16;
        u32 lo = (u32)f2bf(acc[m][n][0] + b0) | ((u32)f2bf(acc[m][n][1] + b1) << 16);
        u32 hi = (u32)f2bf(acc[m][n][2] + b2) | ((u32)f2bf(acc[m][n][3] + b3) << 16);
        *(uint2*)(Kbf + ((size_t)b*SEQ + s) * EMB + e) = make_uint2(lo, hi);
      }
    }
  } else {
    #pragma unroll
    for (int m = 0; m < 4; m++) {
      #pragma unroll
      for (int r = 0; r < 4; r++) {
        int e = e0 + m*16 + g4*4 + r;
        float bvv = bv[e];
        #pragma unroll
        for (int n = 0; n < 4; n++) {
          int s = sbase + n*16 + r16;
          Vtb[((size_t)b*EMB + e) * SEQ + s] = f2bf(acc[m][n][r] + bvv);
        }
      }
    }
  }
}

// ---------------- K3a: S = QK^T, E = exp, rowsum ---------------------------
__global__ __launch_bounds__(512) void k_attn_qk(
    const u16* __restrict__ Qbf, const u16* __restrict__ Kbf,
    const int* __restrict__ mask, float* __restrict__ dout, float* __restrict__ invrs)
{
  int b = blockIdx.y, qt = blockIdx.x, qbase = qt * 32;
  int t = threadIdx.x, wv = t >> 6, lane = t & 63, g4 = lane >> 4, r16 = lane & 15;
  int jb = wv * 256;
  int slot = b * NQT + qt;
  u16* Eu = (u16*)dout;
  size_t eb = ((size_t)OUT0 + (size_t)slot * SLOTF) * 2 + 65536;  // upper half of slot

  bf16x8 qf[2][8];
  #pragma unroll
  for (int m = 0; m < 2; m++) {
    const u16* qp = Qbf + ((size_t)b*HW + qbase + m*16 + r16) * EMB + g4*8;
    #pragma unroll
    for (int kk = 0; kk < 8; kk++) qf[m][kk] = ld16(qp + kk*32);
  }
  float rs[2][4] = {};
  const float SC = 0.0625f;  // EMB^-0.5
  #pragma unroll 1
  for (int nch = 0; nch < 4; nch++) {
    f32x4 acc[2][4] = {};
    #pragma unroll
    for (int kk = 0; kk < 8; kk++) {
      bf16x8 kf[4];
      #pragma unroll
      for (int n = 0; n < 4; n++)
        kf[n] = ld16(Kbf + ((size_t)b*SEQ + jb + nch*64 + n*16 + r16) * EMB + kk*32 + g4*8);
      #pragma unroll
      for (int m = 0; m < 2; m++)
        #pragma unroll
        for (int n = 0; n < 4; n++)
          acc[m][n] = MFMA(qf[m][kk], kf[n], acc[m][n]);
    }
    #pragma unroll
    for (int m = 0; m < 2; m++) {
      int li0 = m*16 + g4*4;
      #pragma unroll
      for (int n = 0; n < 4; n++) {
        int j = jb + nch*64 + n*16 + r16;
        const int* mp = mask + ((size_t)b*HW + qbase + li0) * SEQ + j;
        #pragma unroll
        for (int r = 0; r < 4; r++) {
          float s = acc[m][n][r] * SC;
          int mk = mp[(size_t)r * SEQ];
          float e = mk ? 0.f : __expf(s);
          rs[m][r] += e;
          Eu[eb + (size_t)(li0 + r) * 2048 + j] = f2bf(e);
        }
      }
    }
  }
  __shared__ float red[8][32];
  #pragma unroll
  for (int m = 0; m < 2; m++)
    #pragma unroll
    for (int r = 0; r < 4; r++) {
      float v = rs[m][r];
      v += __shfl_xor(v, 1); v += __shfl_xor(v, 2);
      v += __shfl_xor(v, 4); v += __shfl_xor(v, 8);
      if (r16 == 0) red[wv][m*16 + g4*4 + r] = v;
    }
  __syncthreads();
  if (t < 32) {
    float s2 = 0.f;
    #pragma unroll
    for (int w2 = 0; w2 < 8; w2++) s2 += red[w2][t];
    invrs[(size_t)b*HW + qbase + t] = 1.f / s2;
  }
}

// ---------------- K3b: O = (E*inv) V, att = E*inv ---------------------------
__global__ __launch_bounds__(512) void k_attn_pv(
    const u16* __restrict__ Vtb, const float* __restrict__ invrs,
    u16* __restrict__ Obf, float* __restrict__ dout)
{
  int b = blockIdx.y, qt = blockIdx.x, qbase = qt * 32;
  int t = threadIdx.x, wv = t >> 6, lane = t & 63, g4 = lane >> 4, r16 = lane & 15;
  int slot = b * NQT + qt;
  u16* Eu = (u16*)dout;
  size_t eb = ((size_t)OUT0 + (size_t)slot * SLOTF) * 2 + 65536;
  float* attf = dout + OUT0 + (size_t)slot * SLOTF;
  int e0 = wv * 32;
  const u16* Vb = Vtb + (size_t)b * EMB * SEQ;

  f32x4 acc[2][2] = {};
  #pragma unroll 2
  for (int kk = 0; kk < 64; kk++) {
    int ko = kk*32 + g4*8;
    bf16x8 a0 = ld16(Eu + eb + (size_t)(r16) * 2048 + ko);
    bf16x8 a1 = ld16(Eu + eb + (size_t)(16 + r16) * 2048 + ko);
    bf16x8 b0 = ld16(Vb + (size_t)(e0 + r16) * SEQ + ko);
    bf16x8 b1 = ld16(Vb + (size_t)(e0 + 16 + r16) * SEQ + ko);
    acc[0][0] = MFMA(a0, b0, acc[0][0]);
    acc[0][1] = MFMA(a0, b1, acc[0][1]);
    acc[1][0] = MFMA(a1, b0, acc[1][0]);
    acc[1][1] = MFMA(a1, b1, acc[1][1]);
  }
  const float* invp = invrs + (size_t)b*HW + qbase;
  #pragma unroll
  for (int m = 0; m < 2; m++)
    #pragma unroll
    for (int r = 0; r < 4; r++) {
      int li = m*16 + g4*4 + r;
      float iv = invp[li];
      #pragma unroll
      for (int n = 0; n < 2; n++)
        Obf[((size_t)b*HW + qbase + li) * EMB + e0 + n*16 + r16] = f2bf(acc[m][n][r] * iv);
    }
  __syncthreads();
  // att rows 0..15: destination does not overlap E storage (E sits in rows 16..31 bytes)
  #pragma unroll 1
  for (int v = 0; v < 16; v++) {
    uint2 raw = *(const uint2*)(Eu + eb + (size_t)v * 2048 + 4*t);
    float iv = invp[v];
    float4 o = make_float4(bf2f(raw.x & 0xffffu) * iv, bf2f(raw.x >> 16) * iv,
                           bf2f(raw.y & 0xffffu) * iv, bf2f(raw.y >> 16) * iv);
    *(float4*)(attf + (size_t)v * 2048 + 4*t) = o;
  }
  __syncthreads();
  // att rows 16..31 overwrite E storage: read row -> barrier -> write -> barrier
  #pragma unroll 1
  for (int v = 16; v < 32; v++) {
    uint2 raw = *(const uint2*)(Eu + eb + (size_t)v * 2048 + 4*t);
    __syncthreads();
    float iv = invp[v];
    float4 o = make_float4(bf2f(raw.x & 0xffffu) * iv, bf2f(raw.x >> 16) * iv,
                           bf2f(raw.y & 0xffffu) * iv, bf2f(raw.y >> 16) * iv);
    *(float4*)(attf + (size_t)v * 2048 + 4*t) = o;
    __syncthreads();
  }
}

// ---------------- K4: out projection ----------------------------------------
// out[b][c][i] = sum_e Wout[c][e] * O[b][i][e] + b_out[c]
__global__ __launch_bounds__(256) void k_outproj(
    const u16* __restrict__ Obf, const u16* __restrict__ WoutBf,
    const float* __restrict__ bout, float* __restrict__ out)
{
  int b = blockIdx.y, ibase = blockIdx.x * 64;
  int t = threadIdx.x, wv = t >> 6, lane = t & 63, g4 = lane >> 4, r16 = lane & 15;
  int c0 = wv * 64;
  f32x4 acc[4][4] = {};
  #pragma unroll 2
  for (int kk = 0; kk < 8; kk++) {
    bf16x8 a[4];
    #pragma unroll
    for (int m = 0; m < 4; m++)
      a[m] = ld16(WoutBf + (size_t)(c0 + m*16 + r16) * 256 + kk*32 + g4*8);
    bf16x8 bb[4];
    #pragma unroll
    for (int n = 0; n < 4; n++)
      bb[n] = ld16(Obf + ((size_t)b*HW + ibase + n*16 + r16) * EMB + kk*32 + g4*8);
    #pragma unroll
    for (int m = 0; m < 4; m++)
      #pragma unroll
      for (int n = 0; n < 4; n++)
        acc[m][n] = MFMA(a[m], bb[n], acc[m][n]);
  }
  #pragma unroll
  for (int m = 0; m < 4; m++) {
    #pragma unroll
    for (int r = 0; r < 4; r++) {
      int c = c0 + m*16 + g4*4 + r;
      float bo = bout[c];
      #pragma unroll
      for (int n = 0; n < 4; n++) {
        int i = ibase + n*16 + r16;
        out[((size_t)b*CH + c) * HW + i] = acc[m][n][r] + bo;
      }
    }
  }
}

// ---------------- host ------------------------------------------------------
extern "C" void kernel_launch(void* const* d_in, const int* in_sizes, int n_in,
                              void* d_out, int out_size, void* d_ws, size_t ws_size,
                              hipStream_t stream)
{
  const float* x    = (const float*)d_in[0];
  const float* ctx  = (const float*)d_in[1];
  const int*   mask = (const int*)  d_in[2];
  const float* W_in = (const float*)d_in[3];
  const float* b_in = (const float*)d_in[4];
  const float* Wq   = (const float*)d_in[5];
  const float* bq   = (const float*)d_in[6];
  const float* Wk   = (const float*)d_in[7];
  const float* bk   = (const float*)d_in[8];
  const float* Wv   = (const float*)d_in[9];
  const float* bv   = (const float*)d_in[10];
  const float* Wout = (const float*)d_in[11];
  const float* bout = (const float*)d_in[12];
  float* out = (float*)d_out;

  char* ws = (char*)d_ws;
  size_t off = 0;
  auto alloc = [&](size_t bytes) -> void* {
    void* p = ws + off;
    off += (bytes + 255) & ~(size_t)255;
    return p;
  };
  u16*   WqinBf = (u16*)  alloc(256*256*2);
  u16*   WkBf   = (u16*)  alloc(256*128*2);
  u16*   WvBf   = (u16*)  alloc(256*128*2);
  u16*   WoutBf = (u16*)  alloc(256*256*2);
  float* bq_eff = (float*)alloc(256*4);
  float* invrs  = (float*)alloc((size_t)BB*HW*4);
  u16*   Qbf    = (u16*)  alloc((size_t)BB*HW*EMB*2);   // reused as O after k_attn_qk
  u16*   Kbf    = (u16*)  alloc((size_t)BB*SEQ*EMB*2);
  u16*   Vtb    = (u16*)  alloc((size_t)BB*EMB*SEQ*2);
  if (off > ws_size) return;  // diagnostic bail: absmax will equal max|ref|

  k_prep<<<dim3(320), dim3(256), 0, stream>>>(Wq, W_in, b_in, bq, Wk, Wv, Wout,
                                              WqinBf, WkBf, WvBf, WoutBf, bq_eff);
  k_qproj<<<dim3(36, 16), dim3(256), 0, stream>>>(x, WqinBf, bq_eff, Qbf);
  k_kvproj<<<dim3(32, 16), dim3(512), 0, stream>>>(ctx, WkBf, WvBf, bk, bv, Kbf, Vtb);
  k_attn_qk<<<dim3(NQT, 16), dim3(512), 0, stream>>>(Qbf, Kbf, mask, out, invrs);
  k_attn_pv<<<dim3(NQT, 16), dim3(512), 0, stream>>>(Vtb, invrs, Qbf /*O*/, out);
  k_outproj<<<dim3(36, 16), dim3(256), 0, stream>>>(Qbf /*O*/, WoutBf, bout, out);
}

// Round 2
// 502.270 us; speedup vs baseline: 1.4878x; 1.4878x over previous
//
#include <hip/hip_runtime.h>

typedef unsigned short u16;
typedef unsigned int   u32;
typedef __attribute__((ext_vector_type(8))) __bf16 bf16x8;
typedef __attribute__((ext_vector_type(4))) float  f32x4;

#define BB   16
#define CH   256
#define HW   2304
#define SEQ  2048
#define EMB  256
#define CTXD 128
#define OUT0 9437184   // 16*256*2304, float offset of att region in d_out
#define NQT  72        // HW/32
#define SLOTF 65536    // floats per att slot (32*2048)

#define MFMA(a,b,c) __builtin_amdgcn_mfma_f32_16x16x32_bf16(a,b,c,0,0,0)

__device__ __forceinline__ u16 f2bf(float f){
  u32 u = __builtin_bit_cast(u32, f);
  u += 0x7fffu + ((u >> 16) & 1u);
  return (u16)(u >> 16);
}
__device__ __forceinline__ float bf2f(u32 us){ return __builtin_bit_cast(float, us << 16); }

__device__ __forceinline__ bf16x8 ld16(const u16* p){
  uint4 q = *reinterpret_cast<const uint4*>(p);
  return __builtin_bit_cast(bf16x8, q);
}
__device__ __forceinline__ bf16x8 mk8(float a0,float a1,float a2,float a3,
                                      float a4,float a5,float a6,float a7){
  uint4 q;
  q.x = (u32)f2bf(a0) | ((u32)f2bf(a1) << 16);
  q.y = (u32)f2bf(a2) | ((u32)f2bf(a3) << 16);
  q.z = (u32)f2bf(a4) | ((u32)f2bf(a5) << 16);
  q.w = (u32)f2bf(a6) | ((u32)f2bf(a7) << 16);
  return __builtin_bit_cast(bf16x8, q);
}

// ---------------- K0: weight prep -------------------------------------------
__global__ __launch_bounds__(256) void k_prep(
    const float* __restrict__ Wq, const float* __restrict__ W_in,
    const float* __restrict__ b_in, const float* __restrict__ bq,
    const float* __restrict__ Wk, const float* __restrict__ Wv,
    const float* __restrict__ Wout,
    u16* __restrict__ WqinBf, u16* __restrict__ WkBf, u16* __restrict__ WvBf,
    u16* __restrict__ WoutBf, float* __restrict__ bq_eff)
{
  int blk = blockIdx.x, t = threadIdx.x;
  if (blk < 256) {
    int e = blk, c = t;
    float s = 0.f;
    for (int f = 0; f < 256; f++) s += Wq[e*256+f] * W_in[f*256+c];
    WqinBf[e*256+c] = f2bf(s);
    if (t == 0) {
      float bb = bq[e];
      for (int f = 0; f < 256; f++) bb += Wq[e*256+f] * b_in[f];
      bq_eff[e] = bb;
    }
  } else {
    u32 flat = (u32)(blk - 256) * 256 + t;
    for (u32 idx = flat; idx < 131072u; idx += 16384u) {
      if (idx < 32768u)       WkBf[idx]          = f2bf(Wk[idx]);
      else if (idx < 65536u)  WvBf[idx - 32768u] = f2bf(Wv[idx - 32768u]);
      else                    WoutBf[idx - 65536u] = f2bf(Wout[idx - 65536u]);
    }
  }
}

// ---------------- K1: Q projection ------------------------------------------
__global__ __launch_bounds__(256) void k_qproj(
    const float* __restrict__ x, const u16* __restrict__ WqinBf,
    const float* __restrict__ bq_eff, u16* __restrict__ Qbf)
{
  int b = blockIdx.y, ibase = blockIdx.x * 64;
  int t = threadIdx.x, wv = t >> 6, lane = t & 63, g4 = lane >> 4, r16 = lane & 15;
  int e0 = wv * 64;
  f32x4 acc[4][4] = {};
  #pragma unroll 2
  for (int kk = 0; kk < 8; kk++) {
    bf16x8 a[4];
    #pragma unroll
    for (int m = 0; m < 4; m++)
      a[m] = ld16(WqinBf + (size_t)(e0 + m*16 + r16) * 256 + kk*32 + g4*8);
    bf16x8 bb[4];
    #pragma unroll
    for (int n = 0; n < 4; n++) {
      const float* xp = x + ((size_t)b*CH + kk*32 + g4*8) * HW + ibase + n*16 + r16;
      bb[n] = mk8(xp[0], xp[HW], xp[2*HW], xp[3*HW], xp[4*HW], xp[5*HW], xp[6*HW], xp[7*HW]);
    }
    #pragma unroll
    for (int m = 0; m < 4; m++)
      #pragma unroll
      for (int n = 0; n < 4; n++)
        acc[m][n] = MFMA(a[m], bb[n], acc[m][n]);
  }
  #pragma unroll
  for (int m = 0; m < 4; m++) {
    int e = e0 + m*16 + g4*4;
    float b0 = bq_eff[e], b1 = bq_eff[e+1], b2 = bq_eff[e+2], b3 = bq_eff[e+3];
    #pragma unroll
    for (int n = 0; n < 4; n++) {
      int i = ibase + n*16 + r16;
      u32 lo = (u32)f2bf(acc[m][n][0] + b0) | ((u32)f2bf(acc[m][n][1] + b1) << 16);
      u32 hi = (u32)f2bf(acc[m][n][2] + b2) | ((u32)f2bf(acc[m][n][3] + b3) << 16);
      *(uint2*)(Qbf + ((size_t)b*HW + i) * EMB + e) = make_uint2(lo, hi);
    }
  }
}

// ---------------- K2: K & V projections -------------------------------------
__global__ __launch_bounds__(512) void k_kvproj(
    const float* __restrict__ ctx, const u16* __restrict__ WkBf, const u16* __restrict__ WvBf,
    const float* __restrict__ bk, const float* __restrict__ bv,
    u16* __restrict__ Kbf, u16* __restrict__ Vtb)
{
  int b = blockIdx.y, sbase = blockIdx.x * 64;
  int t = threadIdx.x, wv = t >> 6, lane = t & 63, g4 = lane >> 4, r16 = lane & 15;
  bool isV = wv >= 4;
  int e0 = (wv & 3) * 64;
  const u16* Wsel = isV ? WvBf : WkBf;
  f32x4 acc[4][4] = {};
  #pragma unroll
  for (int kk = 0; kk < 4; kk++) {
    bf16x8 a[4];
    #pragma unroll
    for (int m = 0; m < 4; m++)
      a[m] = ld16(Wsel + (size_t)(e0 + m*16 + r16) * 128 + kk*32 + g4*8);
    bf16x8 bb[4];
    #pragma unroll
    for (int n = 0; n < 4; n++) {
      const float* cp = ctx + ((size_t)b*SEQ + sbase + n*16 + r16) * CTXD + kk*32 + g4*8;
      float4 lo = *(const float4*)cp;
      float4 hi = *(const float4*)(cp + 4);
      bb[n] = mk8(lo.x, lo.y, lo.z, lo.w, hi.x, hi.y, hi.z, hi.w);
    }
    #pragma unroll
    for (int m = 0; m < 4; m++)
      #pragma unroll
      for (int n = 0; n < 4; n++)
        acc[m][n] = MFMA(a[m], bb[n], acc[m][n]);
  }
  if (!isV) {
    #pragma unroll
    for (int m = 0; m < 4; m++) {
      int e = e0 + m*16 + g4*4;
      float b0 = bk[e], b1 = bk[e+1], b2 = bk[e+2], b3 = bk[e+3];
      #pragma unroll
      for (int n = 0; n < 4; n++) {
        int s = sbase + n*16 + r16;
        u32 lo = (u32)f2bf(acc[m][n][0] + b0) | ((u32)f2bf(acc[m][n][1] + b1) << 16);
        u32 hi = (u32)f2bf(acc[m][n][2] + b2) | ((u32)f2bf(acc[m][n][3] + b3) << 16);
        *(uint2*)(Kbf + ((size_t)b*SEQ + s) * EMB + e) = make_uint2(lo, hi);
      }
    }
  } else {
    #pragma unroll
    for (int m = 0; m < 4; m++) {
      #pragma unroll
      for (int r = 0; r < 4; r++) {
        int e = e0 + m*16 + g4*4 + r;
        float bvv = bv[e];
        #pragma unroll
        for (int n = 0; n < 4; n++) {
          int s = sbase + n*16 + r16;
          Vtb[((size_t)b*EMB + e) * SEQ + s] = f2bf(acc[m][n][r] + bvv);
        }
      }
    }
  }
}

// ---------------- K3: fused attention (QK^T + exp + PV + att write) ---------
// One block per (b, 32-row q-tile). E lives in LDS (XOR-swizzled).
__global__ __launch_bounds__(512) void k_attn(
    const u16* __restrict__ Qbf, const u16* __restrict__ Kbf,
    const u16* __restrict__ Vtb, const int* __restrict__ mask,
    float* __restrict__ dout, u16* __restrict__ Obf)
{
  __shared__ u16 Els[32][2048];     // 128 KiB, swizzled: byte ^= (row&7)<<4
  __shared__ float red[8][32];
  __shared__ float invs[32];

  int b = blockIdx.y, qt = blockIdx.x, qbase = qt * 32;
  int t = threadIdx.x, wv = t >> 6, lane = t & 63, g4 = lane >> 4, r16 = lane & 15;
  int jb = wv * 256;
  int slot = b * NQT + qt;
  float* attf = dout + OUT0 + (size_t)slot * SLOTF;

  // ---- phase 1: S = QK^T (this wave's 256-j chunk), mask, exp -> LDS ----
  bf16x8 qf[2][8];
  #pragma unroll
  for (int m = 0; m < 2; m++) {
    const u16* qp = Qbf + ((size_t)b*HW + qbase + m*16 + r16) * EMB + g4*8;
    #pragma unroll
    for (int kk = 0; kk < 8; kk++) qf[m][kk] = ld16(qp + kk*32);
  }
  float rs[2][4] = {};
  const float SC = 0.0625f;  // EMB^-0.5
  #pragma unroll 1
  for (int nch = 0; nch < 4; nch++) {
    f32x4 acc[2][4] = {};
    #pragma unroll
    for (int kk = 0; kk < 8; kk++) {
      bf16x8 kf[4];
      #pragma unroll
      for (int n = 0; n < 4; n++)
        kf[n] = ld16(Kbf + ((size_t)b*SEQ + jb + nch*64 + n*16 + r16) * EMB + kk*32 + g4*8);
      #pragma unroll
      for (int m = 0; m < 2; m++)
        #pragma unroll
        for (int n = 0; n < 4; n++)
          acc[m][n] = MFMA(qf[m][kk], kf[n], acc[m][n]);
    }
    #pragma unroll
    for (int m = 0; m < 2; m++) {
      int li0 = m*16 + g4*4;
      #pragma unroll
      for (int n = 0; n < 4; n++) {
        int j = jb + nch*64 + n*16 + r16;
        const int* mp = mask + ((size_t)b*HW + qbase + li0) * SEQ + j;
        #pragma unroll
        for (int r = 0; r < 4; r++) {
          float s = acc[m][n][r] * SC;
          int mk = mp[(size_t)r * SEQ];
          float e = mk ? 0.f : __expf(s);
          rs[m][r] += e;
          int row = li0 + r;
          u32 bo = (u32)(j * 2) ^ ((u32)(row & 7) << 4);
          *(u16*)((char*)&Els[row][0] + bo) = f2bf(e);
        }
      }
    }
  }
  // rowsum: reduce across r16 lanes, then across waves via LDS
  #pragma unroll
  for (int m = 0; m < 2; m++)
    #pragma unroll
    for (int r = 0; r < 4; r++) {
      float v = rs[m][r];
      v += __shfl_xor(v, 1); v += __shfl_xor(v, 2);
      v += __shfl_xor(v, 4); v += __shfl_xor(v, 8);
      if (r16 == 0) red[wv][m*16 + g4*4 + r] = v;
    }
  __syncthreads();
  if (t < 32) {
    float s2 = 0.f;
    #pragma unroll
    for (int w2 = 0; w2 < 8; w2++) s2 += red[w2][t];
    invs[t] = 1.f / s2;
  }
  __syncthreads();

  // ---- phase 2: O = (E*inv) V  with att = E*inv write interleaved ----
  int e0 = wv * 32;
  const u16* Vb = Vtb + (size_t)b * EMB * SEQ;
  int arow = t >> 4;                 // 0..31 (per-thread att row)
  int acol = (t & 15) * 2;           // 0..30 (pair of att cols within 32-slice)
  float ivA = invs[arow];
  const char* ErowA = (const char*)&Els[arow][0];
  u32 axor = (u32)(arow & 7) << 4;
  const char* E0p = (const char*)&Els[r16][0];
  const char* E1p = (const char*)&Els[16 + r16][0];
  u32 rxor = (u32)(r16 & 7) << 4;    // same for row r16 and 16+r16

  f32x4 acc2[2][2] = {};
  #pragma unroll 2
  for (int kk = 0; kk < 64; kk++) {
    int ko = kk*32 + g4*8;
    u32 bo = (u32)(ko * 2) ^ rxor;
    bf16x8 a0 = __builtin_bit_cast(bf16x8, *(const uint4*)(E0p + bo));
    bf16x8 a1 = __builtin_bit_cast(bf16x8, *(const uint4*)(E1p + bo));
    bf16x8 b0 = ld16(Vb + (size_t)(e0 + r16) * SEQ + ko);
    bf16x8 b1 = ld16(Vb + (size_t)(e0 + 16 + r16) * SEQ + ko);
    acc2[0][0] = MFMA(a0, b0, acc2[0][0]);
    acc2[0][1] = MFMA(a0, b1, acc2[0][1]);
    acc2[1][0] = MFMA(a1, b0, acc2[1][0]);
    acc2[1][1] = MFMA(a1, b1, acc2[1][1]);
    // att slice for cols [kk*32, kk*32+32): 2 floats per thread, coalesced 128B/row
    u32 abo = (u32)(kk*64 + (t & 15)*4) ^ axor;
    u32 araw = *(const u32*)(ErowA + abo);
    float2 av;
    av.x = bf2f(araw & 0xffffu) * ivA;
    av.y = bf2f(araw >> 16) * ivA;
    *(float2*)(attf + (size_t)arow * 2048 + kk*32 + acol) = av;
  }
  #pragma unroll
  for (int m = 0; m < 2; m++)
    #pragma unroll
    for (int r = 0; r < 4; r++) {
      int li = m*16 + g4*4 + r;
      float iv = invs[li];
      #pragma unroll
      for (int n = 0; n < 2; n++)
        Obf[((size_t)b*HW + qbase + li) * EMB + e0 + n*16 + r16] = f2bf(acc2[m][n][r] * iv);
    }
}

// ---------------- K4: out projection ----------------------------------------
__global__ __launch_bounds__(256) void k_outproj(
    const u16* __restrict__ Obf, const u16* __restrict__ WoutBf,
    const float* __restrict__ bout, float* __restrict__ out)
{
  int b = blockIdx.y, ibase = blockIdx.x * 64;
  int t = threadIdx.x, wv = t >> 6, lane = t & 63, g4 = lane >> 4, r16 = lane & 15;
  int c0 = wv * 64;
  f32x4 acc[4][4] = {};
  #pragma unroll 2
  for (int kk = 0; kk < 8; kk++) {
    bf16x8 a[4];
    #pragma unroll
    for (int m = 0; m < 4; m++)
      a[m] = ld16(WoutBf + (size_t)(c0 + m*16 + r16) * 256 + kk*32 + g4*8);
    bf16x8 bb[4];
    #pragma unroll
    for (int n = 0; n < 4; n++)
      bb[n] = ld16(Obf + ((size_t)b*HW + ibase + n*16 + r16) * EMB + kk*32 + g4*8);
    #pragma unroll
    for (int m = 0; m < 4; m++)
      #pragma unroll
      for (int n = 0; n < 4; n++)
        acc[m][n] = MFMA(a[m], bb[n], acc[m][n]);
  }
  #pragma unroll
  for (int m = 0; m < 4; m++) {
    #pragma unroll
    for (int r = 0; r < 4; r++) {
      int c = c0 + m*16 + g4*4 + r;
      float bo = bout[c];
      #pragma unroll
      for (int n = 0; n < 4; n++) {
        int i = ibase + n*16 + r16;
        out[((size_t)b*CH + c) * HW + i] = acc[m][n][r] + bo;
      }
    }
  }
}

// ---------------- host ------------------------------------------------------
extern "C" void kernel_launch(void* const* d_in, const int* in_sizes, int n_in,
                              void* d_out, int out_size, void* d_ws, size_t ws_size,
                              hipStream_t stream)
{
  const float* x    = (const float*)d_in[0];
  const float* ctx  = (const float*)d_in[1];
  const int*   mask = (const int*)  d_in[2];
  const float* W_in = (const float*)d_in[3];
  const float* b_in = (const float*)d_in[4];
  const float* Wq   = (const float*)d_in[5];
  const float* bq   = (const float*)d_in[6];
  const float* Wk   = (const float*)d_in[7];
  const float* bk   = (const float*)d_in[8];
  const float* Wv   = (const float*)d_in[9];
  const float* bv   = (const float*)d_in[10];
  const float* Wout = (const float*)d_in[11];
  const float* bout = (const float*)d_in[12];
  float* out = (float*)d_out;

  char* ws = (char*)d_ws;
  size_t off = 0;
  auto alloc = [&](size_t bytes) -> void* {
    void* p = ws + off;
    off += (bytes + 255) & ~(size_t)255;
    return p;
  };
  u16*   WqinBf = (u16*)  alloc(256*256*2);
  u16*   WkBf   = (u16*)  alloc(256*128*2);
  u16*   WvBf   = (u16*)  alloc(256*128*2);
  u16*   WoutBf = (u16*)  alloc(256*256*2);
  float* bq_eff = (float*)alloc(256*4);
  u16*   Qbf    = (u16*)  alloc((size_t)BB*HW*EMB*2);   // reused as O by k_attn
  u16*   Kbf    = (u16*)  alloc((size_t)BB*SEQ*EMB*2);
  u16*   Vtb    = (u16*)  alloc((size_t)BB*EMB*SEQ*2);
  if (off > ws_size) return;  // diagnostic bail

  k_prep<<<dim3(320), dim3(256), 0, stream>>>(Wq, W_in, b_in, bq, Wk, Wv, Wout,
                                              WqinBf, WkBf, WvBf, WoutBf, bq_eff);
  k_qproj<<<dim3(36, 16), dim3(256), 0, stream>>>(x, WqinBf, bq_eff, Qbf);
  k_kvproj<<<dim3(32, 16), dim3(512), 0, stream>>>(ctx, WkBf, WvBf, bk, bv, Kbf, Vtb);
  k_attn<<<dim3(NQT, 16), dim3(512), 0, stream>>>(Qbf, Kbf, Vtb, mask, out, Qbf /*O*/);
  k_outproj<<<dim3(36, 16), dim3(256), 0, stream>>>(Qbf /*O*/, WoutBf, bout, out);
}